// Round 14
// baseline (252.625 us; speedup 1.0000x reference)
//
#include <hip/hip_runtime.h>

#define N_NODES 50000
#define N_EDGES 800000
#define DIM 128
#define TOT_EDGES (N_EDGES + N_NODES)
#define LOG2E 1.44269504088896f

// bucketed CSR build
#define BSHIFT 9
#define BNODES 512
#define NB ((N_NODES + BNODES - 1) / BNODES)  // 98
#define BCAP 16384
#define EPB 4096
#define EPT 16
#define NBLK_A ((TOT_EDGES + EPB - 1) / EPB)  // 208

typedef __attribute__((ext_vector_type(8))) _Float16 f16x8;
typedef __attribute__((ext_vector_type(2))) _Float16 h2;
typedef __attribute__((ext_vector_type(4))) float f32x4;
typedef decltype(__builtin_amdgcn_cvt_pkrtz(0.f, 0.f)) fp16v2;  // __fp16 x2

__device__ inline uint h2u(h2 v) { return __builtin_bit_cast(uint, v); }
__device__ inline h2 u2h(uint v) { return __builtin_bit_cast(h2, v); }
__device__ inline uint pk2u(fp16v2 v) { return __builtin_bit_cast(uint, v); }

// sum over each 16-lane group via DPP row rotations (pure VALU)
__device__ inline float rowsum16(float v) {
  int x;
  x = __builtin_amdgcn_update_dpp(0, __float_as_int(v), 0x128, 0xF, 0xF, true);  // row_ror:8
  v += __int_as_float(x);
  x = __builtin_amdgcn_update_dpp(0, __float_as_int(v), 0x124, 0xF, 0xF, true);  // row_ror:4
  v += __int_as_float(x);
  x = __builtin_amdgcn_update_dpp(0, __float_as_int(v), 0x122, 0xF, 0xF, true);  // row_ror:2
  v += __int_as_float(x);
  x = __builtin_amdgcn_update_dpp(0, __float_as_int(v), 0x121, 0xF, 0xF, true);  // row_ror:1
  v += __int_as_float(x);
  return v;
}

// sum over each 4-lane quad via quad_perm DPP (xor1 then xor2)
__device__ inline float quadsum4(float v) {
  int x;
  x = __builtin_amdgcn_update_dpp(0, __float_as_int(v), 0xB1, 0xF, 0xF, true);  // quad_perm [1,0,3,2]
  v += __int_as_float(x);
  x = __builtin_amdgcn_update_dpp(0, __float_as_int(v), 0x4E, 0xF, 0xF, true);  // quad_perm [2,3,0,1]
  v += __int_as_float(x);
  return v;
}

// ---------------- conversions (+ bcnt zero: runs before partA) ----------------

__global__ __launch_bounds__(256) void convx_kernel(const float* __restrict__ x,
                                                    uint* __restrict__ xb,
                                                    int* __restrict__ bcnt) {
  if (blockIdx.x == 0 && threadIdx.x < NB) bcnt[threadIdx.x] = 0;
  int t = blockIdx.x * 256 + threadIdx.x;
  if (t < N_NODES * (DIM / 2)) {
    float2 v = ((const float2*)x)[t];
    xb[t] = pk2u(__builtin_amdgcn_cvt_pkrtz(v.x, v.y));
  }
}

// Wt: [l][2][n=128][k=128] f16 from W[l][k][n] f32; plus attc + col pad
__global__ __launch_bounds__(256) void convwa_kernel(const float* __restrict__ Wl,
                                                     const float* __restrict__ Wr,
                                                     ushort* __restrict__ Wt,
                                                     const float* __restrict__ att,
                                                     uint* __restrict__ attc,
                                                     uint* __restrict__ col) {
  int t = blockIdx.x * 256 + threadIdx.x;
  if (blockIdx.x == 0) {
    int u = threadIdx.x;
    if (u < 192) {  // attc[l][64], log2e folded
      float a0 = att[2 * u] * LOG2E, a1 = att[2 * u + 1] * LOG2E;
      attc[u] = pk2u(__builtin_amdgcn_cvt_pkrtz(a0, a1));
    }
    if (u < 64) col[TOT_EDGES + u] = 0u;  // valid pad: clamp-free lookahead
  }
  if (t >= 3 * 2 * DIM * DIM) return;
  int k = t & 127;
  int n = (t >> 7) & 127;
  int w = (t >> 14) & 1;
  int l = t >> 15;
  const float* W = w ? Wr : Wl;
  _Float16 h = (_Float16)W[l * DIM * DIM + k * DIM + n];
  Wt[t] = __builtin_bit_cast(ushort, h);
}

// ---------------- CSR build: phase A — bucket partition ----------------
// bbuf entry packed in 4B: (src << 9) | (d & 511)

__global__ __launch_bounds__(256) void partA_kernel(const int* __restrict__ srcArr,
                                                    const int* __restrict__ dstArr,
                                                    int* __restrict__ bcnt,
                                                    uint* __restrict__ bbuf) {
  int tid = threadIdx.x;
  int e0 = blockIdx.x * EPB;
  __shared__ int hist[NB], base[NB], loff[NB];
  if (tid < NB) { hist[tid] = 0; loff[tid] = 0; }
  __syncthreads();

  int sv[EPT], dv[EPT];
#pragma unroll
  for (int i = 0; i < EPT; ++i) {
    int e = e0 + i * 256 + tid;
    int s = 0, d = -1;
    if (e < TOT_EDGES) {
      if (e < N_EDGES) { s = srcArr[e]; d = dstArr[e]; }
      else { s = e - N_EDGES; d = s; }
    }
    sv[i] = s; dv[i] = d;
    if (d >= 0) atomicAdd(&hist[d >> BSHIFT], 1);
  }
  __syncthreads();
  if (tid < NB) {
    int h = hist[tid];
    if (h > 0) base[tid] = atomicAdd(&bcnt[tid], h);
  }
  __syncthreads();
#pragma unroll
  for (int i = 0; i < EPT; ++i) {
    int d = dv[i];
    if (d >= 0) {
      int b = d >> BSHIFT;
      int p = atomicAdd(&loff[b], 1);
      bbuf[(size_t)b * BCAP + base[b] + p] = ((uint)sv[i] << 9) | (uint)(d & (BNODES - 1));
    }
  }
}

// ---------------- CSR build: phase B (scan of bcnt done per-block) ----------

__global__ __launch_bounds__(512) void partB_kernel(const uint* __restrict__ bbuf,
                                                    const int* __restrict__ bcnt,
                                                    int* __restrict__ rowptr,
                                                    uint* __restrict__ col) {
  int b = blockIdx.x, tid = threadIdx.x;

  // block-redundant exclusive scan of the 98 bucket counts -> this bucket's base
  __shared__ int s[128];
  if (tid < 128) s[tid] = (tid < NB) ? bcnt[tid] : 0;
  __syncthreads();
  for (int off = 1; off < 128; off <<= 1) {
    int t = 0;
    if (tid < 128 && tid >= off) t = s[tid - off];
    __syncthreads();
    if (tid < 128) s[tid] += t;
    __syncthreads();
  }
  int cb = (b > 0) ? s[b - 1] : 0;
  int m = bcnt[b];
  if (b == 0 && tid == 0) rowptr[N_NODES] = TOT_EDGES;
  const uint* buf = bbuf + (size_t)b * BCAP;

  __shared__ int cnt[BNODES], scn[BNODES], cur[BNODES];
  cnt[tid] = 0;
  __syncthreads();
  for (int e = tid; e < m; e += 512) {
    atomicAdd(&cnt[buf[e] & (BNODES - 1)], 1);
  }
  __syncthreads();
  int c = cnt[tid];
  scn[tid] = c;
  __syncthreads();
  for (int off = 1; off < BNODES; off <<= 1) {
    int t = (tid >= off) ? scn[tid - off] : 0;
    __syncthreads();
    scn[tid] += t;
    __syncthreads();
  }
  int excl = scn[tid] - c;
  int node = b * BNODES + tid;
  if (node < N_NODES) rowptr[node] = cb + excl;
  cur[tid] = excl;
  __syncthreads();
  for (int e = tid; e < m; e += 512) {
    uint sd = buf[e];
    int p = atomicAdd(&cur[sd & (BNODES - 1)], 1);
    col[cb + p] = (sd >> 9) << 4;  // prescaled uint4-element index (src*16)
  }
}

// ---------------- MFMA dual GEMM (f16) ----------------
// M=32 per block (1563 blocks), 4 waves: (Wl/Wr) x (n0 = 0/64). bfrag
// streamed per-nt from L1 (W slice 16KB, L1-resident) instead of held in
// VGPRs -> ~100 VGPRs -> 4 waves/SIMD. afrag double-buffered across mt.

__global__ __launch_bounds__(256) void gemm_mfma_kernel(
    const uint* __restrict__ xb,     // [N][64] f16 pairs
    const ushort* __restrict__ Wt,   // [2][128][128] f16, n-major (this layer)
    const float* __restrict__ bl, const float* __restrict__ br,
    uint* __restrict__ xl, uint* __restrict__ xr) {
  int wave = threadIdx.x >> 6, lane = threadIdx.x & 63;
  int lr = lane & 15, kq = lane >> 4;
  int m0 = blockIdx.x * 32;

  const ushort* W = Wt + (wave >> 1) * (DIM * DIM);
  const float* bias = (wave >> 1) ? br : bl;
  uint* outp = (wave >> 1) ? xr : xl;
  int n0 = (wave & 1) * 64;
  const ushort* xbp = (const ushort*)xb;

  f32x4 acc[2][4];
#pragma unroll
  for (int mt = 0; mt < 2; ++mt)
#pragma unroll
    for (int nt = 0; nt < 4; ++nt)
      acc[mt][nt] = (f32x4){0.f, 0.f, 0.f, 0.f};

  f16x8 af[4];
  {
    int m = m0 + lr;
    int mc = m < N_NODES ? m : N_NODES - 1;
#pragma unroll
    for (int kt = 0; kt < 4; ++kt)
      af[kt] = *(const f16x8*)(xbp + (size_t)mc * DIM + kt * 32 + kq * 8);
  }
#pragma unroll
  for (int mt = 0; mt < 2; ++mt) {
    f16x8 afn[4];
    if (mt < 1) {
      int m2 = m0 + 16 + lr;
      int mc2 = m2 < N_NODES ? m2 : N_NODES - 1;
#pragma unroll
      for (int kt = 0; kt < 4; ++kt)
        afn[kt] = *(const f16x8*)(xbp + (size_t)mc2 * DIM + kt * 32 + kq * 8);
    }
#pragma unroll
    for (int nt = 0; nt < 4; ++nt) {
      f16x8 bf[4];
#pragma unroll
      for (int kt = 0; kt < 4; ++kt)
        bf[kt] = *(const f16x8*)(W + (n0 + nt * 16 + lr) * DIM + kt * 32 + kq * 8);
#pragma unroll
      for (int kt = 0; kt < 4; ++kt)
        acc[mt][nt] = __builtin_amdgcn_mfma_f32_16x16x32_f16(bf[kt], af[kt],
                                                             acc[mt][nt], 0, 0, 0);
    }
    if (mt < 1) {
      af[0] = afn[0]; af[1] = afn[1]; af[2] = afn[2]; af[3] = afn[3];
    }
  }

#pragma unroll
  for (int mt = 0; mt < 2; ++mt) {
    int m = m0 + mt * 16 + lr;
    if (m < N_NODES) {
#pragma unroll
      for (int nt = 0; nt < 4; ++nt) {
        int n = n0 + nt * 16 + kq * 4;
        float4 bb = *(const float4*)(bias + n);
        uint2 o;
        o.x = pk2u(__builtin_amdgcn_cvt_pkrtz(acc[mt][nt][0] + bb.x, acc[mt][nt][1] + bb.y));
        o.y = pk2u(__builtin_amdgcn_cvt_pkrtz(acc[mt][nt][2] + bb.z, acc[mt][nt][3] + bb.w));
        *(uint2*)(outp + (size_t)m * (DIM / 2) + (n >> 1)) = o;
      }
    }
  }
}

// ---------------- fused attention + bias + residual + LayerNorm (+ReLU) ----
// 2 waves per block (2 nodes) to lift the 1-wave-workgroup residency cap.
// Per wave: 4 edges/iter, lane = (e4 = lane>>4, j = lane&15), 8 channels/
// lane. Logit reduce = 2 quad_perm DPP. 3-deep gather pipeline; prescaled
// padded col (clamp-free). Packed f16 accumulation.

__global__ __launch_bounds__(128) void att_kernel(
    const uint4* __restrict__ xinb, const uint4* __restrict__ xlb,
    const uint4* __restrict__ xrb, const int* __restrict__ rowptr,
    const uint* __restrict__ col, const uint4* __restrict__ attc,
    const float4* __restrict__ bias, const float4* __restrict__ gamma,
    const float4* __restrict__ beta, uint4* __restrict__ xoutb,
    float4* __restrict__ xoutf, int do_relu) {
  int lane = threadIdx.x & 63;
  uint j = (uint)(lane & 15);
  int e4 = lane >> 4;
  int n = blockIdx.x * 2 + (threadIdx.x >> 6);

  uint4 rq = xrb[(uint)(n * 16) + j];
  uint4 aq = attc[j];
  h2 r2[4] = {u2h(rq.x), u2h(rq.y), u2h(rq.z), u2h(rq.w)};
  h2 at2[4] = {u2h(aq.x), u2h(aq.y), u2h(aq.z), u2h(aq.w)};
  const h2 c02 = {(_Float16)0.2f, (_Float16)0.2f};

  h2 accp[4] = {};
  float den = 0.f;

  int js = rowptr[n], je = rowptr[n + 1];

  uint cA = col[(uint)(js + e4)];
  uint cB = col[(uint)(js + 4 + e4)];
  uint cC = col[(uint)(js + 8 + e4)];
  uint4 gA = xlb[cA + j];
  uint4 gB = xlb[cB + j];

  for (int cbase = js; cbase < je; cbase += 4) {
    uint cD = col[(uint)(cbase + 12 + e4)];
    uint4 gC = xlb[cC + j];

    h2 a0 = u2h(gA.x), a1 = u2h(gA.y), a2 = u2h(gA.z), a3 = u2h(gA.w);
    float p = 0.f;
    {
      h2 s0 = a0 + r2[0], s1 = a1 + r2[1], s2 = a2 + r2[2], s3 = a3 + r2[3];
      h2 m0 = __builtin_elementwise_max(s0, s0 * c02);
      h2 m1 = __builtin_elementwise_max(s1, s1 * c02);
      h2 m2 = __builtin_elementwise_max(s2, s2 * c02);
      h2 m3 = __builtin_elementwise_max(s3, s3 * c02);
      p = __builtin_amdgcn_fdot2(__builtin_bit_cast(fp16v2, m0),
                                 __builtin_bit_cast(fp16v2, at2[0]), p, false);
      p = __builtin_amdgcn_fdot2(__builtin_bit_cast(fp16v2, m1),
                                 __builtin_bit_cast(fp16v2, at2[1]), p, false);
      p = __builtin_amdgcn_fdot2(__builtin_bit_cast(fp16v2, m2),
                                 __builtin_bit_cast(fp16v2, at2[2]), p, false);
      p = __builtin_amdgcn_fdot2(__builtin_bit_cast(fp16v2, m3),
                                 __builtin_bit_cast(fp16v2, at2[3]), p, false);
    }
    p = quadsum4(p);
    float w = (cbase + e4 < je) ? __builtin_amdgcn_exp2f(p) : 0.f;
    den += w;
    _Float16 wh = (_Float16)w;
    h2 w2 = {wh, wh};
    accp[0] = w2 * a0 + accp[0];
    accp[1] = w2 * a1 + accp[1];
    accp[2] = w2 * a2 + accp[2];
    accp[3] = w2 * a3 + accp[3];

    gA = gB; gB = gC; cC = cD;
  }

#pragma unroll
  for (int t = 0; t < 4; ++t) {
    accp[t] += u2h((uint)__shfl_xor((int)h2u(accp[t]), 16, 64));
    accp[t] += u2h((uint)__shfl_xor((int)h2u(accp[t]), 32, 64));
  }
  den += __shfl_xor(den, 16, 64);
  den += __shfl_xor(den, 32, 64);

  float inv = 1.0f / den;
  float acc[8];
#pragma unroll
  for (int t = 0; t < 4; ++t) {
    acc[2 * t] = (float)accp[t].x;
    acc[2 * t + 1] = (float)accp[t].y;
  }

  uint4 xi4 = xinb[(uint)(n * 16) + j];
  h2 xi[4] = {u2h(xi4.x), u2h(xi4.y), u2h(xi4.z), u2h(xi4.w)};
  float4 b0 = bias[2 * j], b1 = bias[2 * j + 1];

  float o[8];
  o[0] = fmaf(acc[0], inv, b0.x + (float)xi[0].x);
  o[1] = fmaf(acc[1], inv, b0.y + (float)xi[0].y);
  o[2] = fmaf(acc[2], inv, b0.z + (float)xi[1].x);
  o[3] = fmaf(acc[3], inv, b0.w + (float)xi[1].y);
  o[4] = fmaf(acc[4], inv, b1.x + (float)xi[2].x);
  o[5] = fmaf(acc[5], inv, b1.y + (float)xi[2].y);
  o[6] = fmaf(acc[6], inv, b1.z + (float)xi[3].x);
  o[7] = fmaf(acc[7], inv, b1.w + (float)xi[3].y);

  float s1 = 0.f, s2 = 0.f;
#pragma unroll
  for (int t = 0; t < 8; ++t) { s1 += o[t]; s2 = fmaf(o[t], o[t], s2); }
  s1 = rowsum16(s1);
  s2 = rowsum16(s2);
  float mean = s1 * (1.0f / DIM);
  float var = s2 * (1.0f / DIM) - mean * mean;
  float rstd = rsqrtf(var + 1e-5f);

  float4 g0 = gamma[2 * j], g1 = gamma[2 * j + 1];
  float4 t0 = beta[2 * j], t1 = beta[2 * j + 1];
  float y[8];
  y[0] = (o[0] - mean) * rstd * g0.x + t0.x;
  y[1] = (o[1] - mean) * rstd * g0.y + t0.y;
  y[2] = (o[2] - mean) * rstd * g0.z + t0.z;
  y[3] = (o[3] - mean) * rstd * g0.w + t0.w;
  y[4] = (o[4] - mean) * rstd * g1.x + t1.x;
  y[5] = (o[5] - mean) * rstd * g1.y + t1.y;
  y[6] = (o[6] - mean) * rstd * g1.z + t1.z;
  y[7] = (o[7] - mean) * rstd * g1.w + t1.w;
  if (do_relu) {
#pragma unroll
    for (int t = 0; t < 8; ++t) y[t] = fmaxf(y[t], 0.f);
  }

  if (e4 == 0) {
    if (xoutb) {
      uint4 ov;
      ov.x = pk2u(__builtin_amdgcn_cvt_pkrtz(y[0], y[1]));
      ov.y = pk2u(__builtin_amdgcn_cvt_pkrtz(y[2], y[3]));
      ov.z = pk2u(__builtin_amdgcn_cvt_pkrtz(y[4], y[5]));
      ov.w = pk2u(__builtin_amdgcn_cvt_pkrtz(y[6], y[7]));
      xoutb[(uint)(n * 16) + j] = ov;
    }
    if (xoutf) {
      xoutf[(uint)(n * 32) + 2 * j] = make_float4(y[0], y[1], y[2], y[3]);
      xoutf[(uint)(n * 32) + 2 * j + 1] = make_float4(y[4], y[5], y[6], y[7]);
    }
  }
}

// ---------------- launch ----------------

extern "C" void kernel_launch(void* const* d_in, const int* in_sizes, int n_in,
                              void* d_out, int out_size, void* d_ws, size_t ws_size,
                              hipStream_t stream) {
  const float* x_in  = (const float*)d_in[0];
  const int*   eidx  = (const int*)d_in[1];
  const float* Wl    = (const float*)d_in[2];
  const float* bl    = (const float*)d_in[3];
  const float* Wr    = (const float*)d_in[4];
  const float* br    = (const float*)d_in[5];
  const float* att   = (const float*)d_in[6];
  const float* bias  = (const float*)d_in[7];
  const float* gamma = (const float*)d_in[8];
  const float* beta  = (const float*)d_in[9];
  float* out = (float*)d_out;

  char* p = (char*)d_ws;
  auto alloc = [&](size_t bytes) {
    char* q = p;
    p += (bytes + 255) & ~(size_t)255;
    return q;
  };
  uint*  xb       = (uint*)alloc((size_t)N_NODES * (DIM / 2) * 4);
  uint*  xlb      = (uint*)alloc((size_t)N_NODES * (DIM / 2) * 4);
  uint*  xrb      = (uint*)alloc((size_t)N_NODES * (DIM / 2) * 4);
  ushort* Wt      = (ushort*)alloc((size_t)3 * 2 * DIM * DIM * 2);
  uint*  attc     = (uint*)alloc((size_t)3 * 64 * 4);
  int*   rowptr   = (int*)alloc((size_t)(N_NODES + 1) * 4);
  uint*  col      = (uint*)alloc((size_t)(TOT_EDGES + 64) * 4);
  uint*  bbuf     = (uint*)alloc((size_t)NB * BCAP * 4);
  int*   bcnt     = (int*)alloc((size_t)NB * 4);

  // prep: 4 dispatches (convx zeroes bcnt; convwa also writes attc + col pad)
  convx_kernel<<<(N_NODES * (DIM / 2) + 255) / 256, 256, 0, stream>>>(x_in, xb, bcnt);
  convwa_kernel<<<(3 * 2 * DIM * DIM + 255) / 256, 256, 0, stream>>>(Wl, Wr, Wt, att, attc, col);
  partA_kernel<<<NBLK_A, 256, 0, stream>>>(eidx, eidx + N_EDGES, bcnt, bbuf);
  partB_kernel<<<NB, 512, 0, stream>>>(bbuf, bcnt, rowptr, col);

  for (int l = 0; l < 3; ++l) {
    gemm_mfma_kernel<<<(N_NODES + 31) / 32, 256, 0, stream>>>(
        xb, Wt + (size_t)l * 2 * DIM * DIM, bl + l * DIM, br + l * DIM, xlb, xrb);
    att_kernel<<<N_NODES / 2, 128, 0, stream>>>(
        (const uint4*)xb, (const uint4*)xlb, (const uint4*)xrb, rowptr, col,
        (const uint4*)(attc + l * 64), (const float4*)(bias + l * DIM),
        (const float4*)(gamma + l * DIM), (const float4*)(beta + l * DIM),
        (l == 2) ? nullptr : (uint4*)xb, (l == 2) ? (float4*)out : nullptr,
        (l != 2) ? 1 : 0);
  }
}

// Round 15
// 238.709 us; speedup vs baseline: 1.0583x; 1.0583x over previous
//
#include <hip/hip_runtime.h>

#define N_NODES 50000
#define N_EDGES 800000
#define DIM 128
#define TOT_EDGES (N_EDGES + N_NODES)
#define LOG2E 1.44269504088896f

// bucketed CSR build
#define BSHIFT 9
#define BNODES 512
#define NB ((N_NODES + BNODES - 1) / BNODES)  // 98
#define BCAP 16384
#define EPB 4096
#define EPT 16
#define NBLK_A ((TOT_EDGES + EPB - 1) / EPB)  // 208
#define CONVX_BLOCKS ((N_NODES * (DIM / 2) + 255) / 256)  // 12500
#define CONVW_BLOCKS ((3 * 2 * DIM * DIM + 255) / 256)    // 384

typedef __attribute__((ext_vector_type(8))) _Float16 f16x8;
typedef __attribute__((ext_vector_type(2))) _Float16 h2;
typedef __attribute__((ext_vector_type(4))) float f32x4;
typedef decltype(__builtin_amdgcn_cvt_pkrtz(0.f, 0.f)) fp16v2;  // __fp16 x2

__device__ inline uint h2u(h2 v) { return __builtin_bit_cast(uint, v); }
__device__ inline h2 u2h(uint v) { return __builtin_bit_cast(h2, v); }
__device__ inline uint pk2u(fp16v2 v) { return __builtin_bit_cast(uint, v); }

// sum over each 16-lane group via DPP row rotations (pure VALU)
__device__ inline float rowsum16(float v) {
  int x;
  x = __builtin_amdgcn_update_dpp(0, __float_as_int(v), 0x128, 0xF, 0xF, true);  // row_ror:8
  v += __int_as_float(x);
  x = __builtin_amdgcn_update_dpp(0, __float_as_int(v), 0x124, 0xF, 0xF, true);  // row_ror:4
  v += __int_as_float(x);
  x = __builtin_amdgcn_update_dpp(0, __float_as_int(v), 0x122, 0xF, 0xF, true);  // row_ror:2
  v += __int_as_float(x);
  x = __builtin_amdgcn_update_dpp(0, __float_as_int(v), 0x121, 0xF, 0xF, true);  // row_ror:1
  v += __int_as_float(x);
  return v;
}

// sum over each 4-lane quad via quad_perm DPP (xor1 then xor2)
__device__ inline float quadsum4(float v) {
  int x;
  x = __builtin_amdgcn_update_dpp(0, __float_as_int(v), 0xB1, 0xF, 0xF, true);  // quad_perm [1,0,3,2]
  v += __int_as_float(x);
  x = __builtin_amdgcn_update_dpp(0, __float_as_int(v), 0x4E, 0xF, 0xF, true);  // quad_perm [2,3,0,1]
  v += __int_as_float(x);
  return v;
}

// ---------------- fused conversions (x->f16, W->Wt, attc, col pad, bcnt=0) ----

__global__ __launch_bounds__(256) void conv_kernel(const float* __restrict__ x,
                                                   uint* __restrict__ xb,
                                                   int* __restrict__ bcnt,
                                                   const float* __restrict__ Wl,
                                                   const float* __restrict__ Wr,
                                                   ushort* __restrict__ Wt,
                                                   const float* __restrict__ att,
                                                   uint* __restrict__ attc,
                                                   uint* __restrict__ col) {
  int b = blockIdx.x;
  if (b < CONVX_BLOCKS) {
    if (b == 0 && threadIdx.x < NB) bcnt[threadIdx.x] = 0;
    int t = b * 256 + threadIdx.x;
    if (t < N_NODES * (DIM / 2)) {
      float2 v = ((const float2*)x)[t];
      xb[t] = pk2u(__builtin_amdgcn_cvt_pkrtz(v.x, v.y));
    }
  } else {
    int bb = b - CONVX_BLOCKS;
    if (bb == 0) {
      int u = threadIdx.x;
      if (u < 192) {  // attc[l][64], log2e folded
        float a0 = att[2 * u] * LOG2E, a1 = att[2 * u + 1] * LOG2E;
        attc[u] = pk2u(__builtin_amdgcn_cvt_pkrtz(a0, a1));
      }
      if (u < 64) col[TOT_EDGES + u] = 0u;  // valid pad: clamp-free lookahead
    }
    int t = bb * 256 + threadIdx.x;
    if (t < 3 * 2 * DIM * DIM) {
      int k = t & 127;
      int n = (t >> 7) & 127;
      int w = (t >> 14) & 1;
      int l = t >> 15;
      const float* W = w ? Wr : Wl;
      _Float16 h = (_Float16)W[l * DIM * DIM + k * DIM + n];
      Wt[t] = __builtin_bit_cast(ushort, h);
    }
  }
}

// ---------------- CSR build: phase A — bucket partition ----------------
// bbuf entry packed in 4B: (src << 9) | (d & 511)

__global__ __launch_bounds__(256) void partA_kernel(const int* __restrict__ srcArr,
                                                    const int* __restrict__ dstArr,
                                                    int* __restrict__ bcnt,
                                                    uint* __restrict__ bbuf) {
  int tid = threadIdx.x;
  int e0 = blockIdx.x * EPB;
  __shared__ int hist[NB], base[NB], loff[NB];
  if (tid < NB) { hist[tid] = 0; loff[tid] = 0; }
  __syncthreads();

  int sv[EPT], dv[EPT];
#pragma unroll
  for (int i = 0; i < EPT; ++i) {
    int e = e0 + i * 256 + tid;
    int s = 0, d = -1;
    if (e < TOT_EDGES) {
      if (e < N_EDGES) { s = srcArr[e]; d = dstArr[e]; }
      else { s = e - N_EDGES; d = s; }
    }
    sv[i] = s; dv[i] = d;
    if (d >= 0) atomicAdd(&hist[d >> BSHIFT], 1);
  }
  __syncthreads();
  if (tid < NB) {
    int h = hist[tid];
    if (h > 0) base[tid] = atomicAdd(&bcnt[tid], h);
  }
  __syncthreads();
#pragma unroll
  for (int i = 0; i < EPT; ++i) {
    int d = dv[i];
    if (d >= 0) {
      int b = d >> BSHIFT;
      int p = atomicAdd(&loff[b], 1);
      bbuf[(size_t)b * BCAP + base[b] + p] = ((uint)sv[i] << 9) | (uint)(d & (BNODES - 1));
    }
  }
}

// ---------------- CSR build: phase B (scan of bcnt done per-block) ----------

__global__ __launch_bounds__(512) void partB_kernel(const uint* __restrict__ bbuf,
                                                    const int* __restrict__ bcnt,
                                                    int* __restrict__ rowptr,
                                                    uint* __restrict__ col) {
  int b = blockIdx.x, tid = threadIdx.x;

  // block-redundant exclusive scan of the 98 bucket counts -> this bucket's base
  __shared__ int s[128];
  if (tid < 128) s[tid] = (tid < NB) ? bcnt[tid] : 0;
  __syncthreads();
  for (int off = 1; off < 128; off <<= 1) {
    int t = 0;
    if (tid < 128 && tid >= off) t = s[tid - off];
    __syncthreads();
    if (tid < 128) s[tid] += t;
    __syncthreads();
  }
  int cb = (b > 0) ? s[b - 1] : 0;
  int m = bcnt[b];
  if (b == 0 && tid == 0) rowptr[N_NODES] = TOT_EDGES;
  const uint* buf = bbuf + (size_t)b * BCAP;

  __shared__ int cnt[BNODES], scn[BNODES], cur[BNODES];
  cnt[tid] = 0;
  __syncthreads();
  for (int e = tid; e < m; e += 512) {
    atomicAdd(&cnt[buf[e] & (BNODES - 1)], 1);
  }
  __syncthreads();
  int c = cnt[tid];
  scn[tid] = c;
  __syncthreads();
  for (int off = 1; off < BNODES; off <<= 1) {
    int t = (tid >= off) ? scn[tid - off] : 0;
    __syncthreads();
    scn[tid] += t;
    __syncthreads();
  }
  int excl = scn[tid] - c;
  int node = b * BNODES + tid;
  if (node < N_NODES) rowptr[node] = cb + excl;
  cur[tid] = excl;
  __syncthreads();
  for (int e = tid; e < m; e += 512) {
    uint sd = buf[e];
    int p = atomicAdd(&cur[sd & (BNODES - 1)], 1);
    col[cb + p] = (sd >> 9) << 4;  // prescaled uint4-element index (src*16)
  }
}

// ---------------- MFMA dual GEMM (f16), afrag software-pipelined ----------------

__global__ __launch_bounds__(256) void gemm_mfma_kernel(
    const uint* __restrict__ xb,     // [N][64] f16 pairs
    const ushort* __restrict__ Wt,   // [2][128][128] f16, n-major (this layer)
    const float* __restrict__ bl, const float* __restrict__ br,
    uint* __restrict__ xl, uint* __restrict__ xr) {
  int wave = threadIdx.x >> 6, lane = threadIdx.x & 63;
  int lr = lane & 15, kq = lane >> 4;
  int m0 = blockIdx.x * 64;

  const ushort* W = Wt + (wave >> 1) * (DIM * DIM);
  const float* bias = (wave >> 1) ? br : bl;
  uint* outp = (wave >> 1) ? xr : xl;
  int n0 = (wave & 1) * 64;
  const ushort* xbp = (const ushort*)xb;

  f16x8 bfrag[4][4];
#pragma unroll
  for (int nt = 0; nt < 4; ++nt)
#pragma unroll
    for (int kt = 0; kt < 4; ++kt)
      bfrag[nt][kt] = *(const f16x8*)(W + (n0 + nt * 16 + lr) * DIM + kt * 32 + kq * 8);

  f32x4 acc[4][4];
#pragma unroll
  for (int mt = 0; mt < 4; ++mt)
#pragma unroll
    for (int nt = 0; nt < 4; ++nt)
      acc[mt][nt] = (f32x4){0.f, 0.f, 0.f, 0.f};

  // software pipeline: afrag for mt+1 issued before mt's MFMA block
  f16x8 af[4];
  {
    int m = m0 + lr;
    int mc = m < N_NODES ? m : N_NODES - 1;
#pragma unroll
    for (int kt = 0; kt < 4; ++kt)
      af[kt] = *(const f16x8*)(xbp + (size_t)mc * DIM + kt * 32 + kq * 8);
  }
#pragma unroll
  for (int mt = 0; mt < 4; ++mt) {
    f16x8 afn[4];
    if (mt < 3) {
      int m2 = m0 + (mt + 1) * 16 + lr;
      int mc2 = m2 < N_NODES ? m2 : N_NODES - 1;
#pragma unroll
      for (int kt = 0; kt < 4; ++kt)
        afn[kt] = *(const f16x8*)(xbp + (size_t)mc2 * DIM + kt * 32 + kq * 8);
    }
#pragma unroll
    for (int nt = 0; nt < 4; ++nt)
#pragma unroll
      for (int kt = 0; kt < 4; ++kt)
        acc[mt][nt] = __builtin_amdgcn_mfma_f32_16x16x32_f16(bfrag[nt][kt], af[kt],
                                                             acc[mt][nt], 0, 0, 0);
    if (mt < 3) {
      af[0] = afn[0]; af[1] = afn[1]; af[2] = afn[2]; af[3] = afn[3];
    }
  }

#pragma unroll
  for (int mt = 0; mt < 4; ++mt) {
    int m = m0 + mt * 16 + lr;
    if (m < N_NODES) {
#pragma unroll
      for (int nt = 0; nt < 4; ++nt) {
        int n = n0 + nt * 16 + kq * 4;
        float4 bb = *(const float4*)(bias + n);
        uint2 o;
        o.x = pk2u(__builtin_amdgcn_cvt_pkrtz(acc[mt][nt][0] + bb.x, acc[mt][nt][1] + bb.y));
        o.y = pk2u(__builtin_amdgcn_cvt_pkrtz(acc[mt][nt][2] + bb.z, acc[mt][nt][3] + bb.w));
        *(uint2*)(outp + (size_t)m * (DIM / 2) + (n >> 1)) = o;
      }
    }
  }
}

// ---------------- fused attention + bias + residual + LayerNorm (+ReLU) ----
// One wave per destination node (dynamic dispatch = load balance). 4 edges/
// iter: lane = (e4 = lane>>4, j = lane&15), 8 channels/lane. Logit reduce =
// 2 quad_perm DPP. DEEP pipeline: gathers 5-deep (issue-to-use = 4 iters),
// cols 7-deep — covers ~1200 cy of L3 random-gather latency at 5 waves/SIMD.
// Prescaled padded col (clamp-free; pad gathers hit row 0 = cache-hot).
// Packed f16 accumulation; f32 epilogue.

__global__ __launch_bounds__(64) void att_kernel(
    const uint4* __restrict__ xinb, const uint4* __restrict__ xlb,
    const uint4* __restrict__ xrb, const int* __restrict__ rowptr,
    const uint* __restrict__ col, const uint4* __restrict__ attc,
    const float4* __restrict__ bias, const float4* __restrict__ gamma,
    const float4* __restrict__ beta, uint4* __restrict__ xoutb,
    float4* __restrict__ xoutf, int do_relu) {
  int lane = threadIdx.x;
  uint j = (uint)(lane & 15);
  int e4 = lane >> 4;
  int n = blockIdx.x;

  uint4 rq = xrb[(uint)(n * 16) + j];
  uint4 aq = attc[j];
  h2 r2[4] = {u2h(rq.x), u2h(rq.y), u2h(rq.z), u2h(rq.w)};
  h2 at2[4] = {u2h(aq.x), u2h(aq.y), u2h(aq.z), u2h(aq.w)};
  const h2 c02 = {(_Float16)0.2f, (_Float16)0.2f};

  h2 accp[4] = {};
  float den = 0.f;

  int js = rowptr[n], je = rowptr[n + 1];

  // prologue: 7 col loads, 5 gathers in flight
  uint c0 = col[(uint)(js + e4)];
  uint c1 = col[(uint)(js + 4 + e4)];
  uint c2 = col[(uint)(js + 8 + e4)];
  uint c3 = col[(uint)(js + 12 + e4)];
  uint c4 = col[(uint)(js + 16 + e4)];
  uint c5 = col[(uint)(js + 20 + e4)];
  uint c6 = col[(uint)(js + 24 + e4)];
  uint4 g0 = xlb[c0 + j];
  uint4 g1 = xlb[c1 + j];
  uint4 g2 = xlb[c2 + j];
  uint4 g3 = xlb[c3 + j];
  uint4 g4 = xlb[c4 + j];

  for (int cbase = js; cbase < je; cbase += 4) {
    uint cn = col[(uint)(cbase + 28 + e4)];
    uint4 gn = xlb[c5 + j];

    h2 a0 = u2h(g0.x), a1 = u2h(g0.y), a2 = u2h(g0.z), a3 = u2h(g0.w);
    float p = 0.f;
    {
      h2 s0 = a0 + r2[0], s1 = a1 + r2[1], s2 = a2 + r2[2], s3 = a3 + r2[3];
      h2 m0 = __builtin_elementwise_max(s0, s0 * c02);
      h2 m1 = __builtin_elementwise_max(s1, s1 * c02);
      h2 m2 = __builtin_elementwise_max(s2, s2 * c02);
      h2 m3 = __builtin_elementwise_max(s3, s3 * c02);
      p = __builtin_amdgcn_fdot2(__builtin_bit_cast(fp16v2, m0),
                                 __builtin_bit_cast(fp16v2, at2[0]), p, false);
      p = __builtin_amdgcn_fdot2(__builtin_bit_cast(fp16v2, m1),
                                 __builtin_bit_cast(fp16v2, at2[1]), p, false);
      p = __builtin_amdgcn_fdot2(__builtin_bit_cast(fp16v2, m2),
                                 __builtin_bit_cast(fp16v2, at2[2]), p, false);
      p = __builtin_amdgcn_fdot2(__builtin_bit_cast(fp16v2, m3),
                                 __builtin_bit_cast(fp16v2, at2[3]), p, false);
    }
    p = quadsum4(p);
    float w = (cbase + e4 < je) ? __builtin_amdgcn_exp2f(p) : 0.f;
    den += w;
    _Float16 wh = (_Float16)w;
    h2 w2 = {wh, wh};
    accp[0] = w2 * a0 + accp[0];
    accp[1] = w2 * a1 + accp[1];
    accp[2] = w2 * a2 + accp[2];
    accp[3] = w2 * a3 + accp[3];

    g0 = g1; g1 = g2; g2 = g3; g3 = g4; g4 = gn;
    c5 = c6; c6 = cn;
  }

  // combine edge-slots (lanes differing in bits 4,5); packed f16 adds
#pragma unroll
  for (int t = 0; t < 4; ++t) {
    accp[t] += u2h((uint)__shfl_xor((int)h2u(accp[t]), 16, 64));
    accp[t] += u2h((uint)__shfl_xor((int)h2u(accp[t]), 32, 64));
  }
  den += __shfl_xor(den, 16, 64);
  den += __shfl_xor(den, 32, 64);

  float inv = 1.0f / den;
  float acc[8];
#pragma unroll
  for (int t = 0; t < 4; ++t) {
    acc[2 * t] = (float)accp[t].x;
    acc[2 * t + 1] = (float)accp[t].y;
  }

  uint4 xi4 = xinb[(uint)(n * 16) + j];
  h2 xi[4] = {u2h(xi4.x), u2h(xi4.y), u2h(xi4.z), u2h(xi4.w)};
  float4 b0 = bias[2 * j], b1 = bias[2 * j + 1];

  float o[8];
  o[0] = fmaf(acc[0], inv, b0.x + (float)xi[0].x);
  o[1] = fmaf(acc[1], inv, b0.y + (float)xi[0].y);
  o[2] = fmaf(acc[2], inv, b0.z + (float)xi[1].x);
  o[3] = fmaf(acc[3], inv, b0.w + (float)xi[1].y);
  o[4] = fmaf(acc[4], inv, b1.x + (float)xi[2].x);
  o[5] = fmaf(acc[5], inv, b1.y + (float)xi[2].y);
  o[6] = fmaf(acc[6], inv, b1.z + (float)xi[3].x);
  o[7] = fmaf(acc[7], inv, b1.w + (float)xi[3].y);

  float s1 = 0.f, s2 = 0.f;
#pragma unroll
  for (int t = 0; t < 8; ++t) { s1 += o[t]; s2 = fmaf(o[t], o[t], s2); }
  s1 = rowsum16(s1);
  s2 = rowsum16(s2);
  float mean = s1 * (1.0f / DIM);
  float var = s2 * (1.0f / DIM) - mean * mean;
  float rstd = rsqrtf(var + 1e-5f);

  float4 g0_ = gamma[2 * j], g1_ = gamma[2 * j + 1];
  float4 t0 = beta[2 * j], t1 = beta[2 * j + 1];
  float y[8];
  y[0] = (o[0] - mean) * rstd * g0_.x + t0.x;
  y[1] = (o[1] - mean) * rstd * g0_.y + t0.y;
  y[2] = (o[2] - mean) * rstd * g0_.z + t0.z;
  y[3] = (o[3] - mean) * rstd * g0_.w + t0.w;
  y[4] = (o[4] - mean) * rstd * g1_.x + t1.x;
  y[5] = (o[5] - mean) * rstd * g1_.y + t1.y;
  y[6] = (o[6] - mean) * rstd * g1_.z + t1.z;
  y[7] = (o[7] - mean) * rstd * g1_.w + t1.w;
  if (do_relu) {
#pragma unroll
    for (int t = 0; t < 8; ++t) y[t] = fmaxf(y[t], 0.f);
  }

  if (e4 == 0) {
    if (xoutb) {
      uint4 ov;
      ov.x = pk2u(__builtin_amdgcn_cvt_pkrtz(y[0], y[1]));
      ov.y = pk2u(__builtin_amdgcn_cvt_pkrtz(y[2], y[3]));
      ov.z = pk2u(__builtin_amdgcn_cvt_pkrtz(y[4], y[5]));
      ov.w = pk2u(__builtin_amdgcn_cvt_pkrtz(y[6], y[7]));
      xoutb[(uint)(n * 16) + j] = ov;
    }
    if (xoutf) {
      xoutf[(uint)(n * 32) + 2 * j] = make_float4(y[0], y[1], y[2], y[3]);
      xoutf[(uint)(n * 32) + 2 * j + 1] = make_float4(y[4], y[5], y[6], y[7]);
    }
  }
}

// ---------------- launch ----------------

extern "C" void kernel_launch(void* const* d_in, const int* in_sizes, int n_in,
                              void* d_out, int out_size, void* d_ws, size_t ws_size,
                              hipStream_t stream) {
  const float* x_in  = (const float*)d_in[0];
  const int*   eidx  = (const int*)d_in[1];
  const float* Wl    = (const float*)d_in[2];
  const float* bl    = (const float*)d_in[3];
  const float* Wr    = (const float*)d_in[4];
  const float* br    = (const float*)d_in[5];
  const float* att   = (const float*)d_in[6];
  const float* bias  = (const float*)d_in[7];
  const float* gamma = (const float*)d_in[8];
  const float* beta  = (const float*)d_in[9];
  float* out = (float*)d_out;

  char* p = (char*)d_ws;
  auto alloc = [&](size_t bytes) {
    char* q = p;
    p += (bytes + 255) & ~(size_t)255;
    return q;
  };
  uint*  xb       = (uint*)alloc((size_t)N_NODES * (DIM / 2) * 4);
  uint*  xlb      = (uint*)alloc((size_t)N_NODES * (DIM / 2) * 4);
  uint*  xrb      = (uint*)alloc((size_t)N_NODES * (DIM / 2) * 4);
  ushort* Wt      = (ushort*)alloc((size_t)3 * 2 * DIM * DIM * 2);
  uint*  attc     = (uint*)alloc((size_t)3 * 64 * 4);
  int*   rowptr   = (int*)alloc((size_t)(N_NODES + 1) * 4);
  uint*  col      = (uint*)alloc((size_t)(TOT_EDGES + 64) * 4);
  uint*  bbuf     = (uint*)alloc((size_t)NB * BCAP * 4);
  int*   bcnt     = (int*)alloc((size_t)NB * 4);

  // prep: 3 dispatches
  conv_kernel<<<CONVX_BLOCKS + CONVW_BLOCKS, 256, 0, stream>>>(
      x_in, xb, bcnt, Wl, Wr, Wt, att, attc, col);
  partA_kernel<<<NBLK_A, 256, 0, stream>>>(eidx, eidx + N_EDGES, bcnt, bbuf);
  partB_kernel<<<NB, 512, 0, stream>>>(bbuf, bcnt, rowptr, col);

  for (int l = 0; l < 3; ++l) {
    gemm_mfma_kernel<<<(N_NODES + 63) / 64, 256, 0, stream>>>(
        xb, Wt + (size_t)l * 2 * DIM * DIM, bl + l * DIM, br + l * DIM, xlb, xrb);
    att_kernel<<<N_NODES, 64, 0, stream>>>(
        (const uint4*)xb, (const uint4*)xlb, (const uint4*)xrb, rowptr, col,
        (const uint4*)(attc + l * 64), (const float4*)(bias + l * DIM),
        (const float4*)(gamma + l * DIM), (const float4*)(beta + l * DIM),
        (l == 2) ? nullptr : (uint4*)xb, (l == 2) ? (float4*)out : nullptr,
        (l != 2) ? 1 : 0);
  }
}